// Round 3
// baseline (3662.275 us; speedup 1.0000x reference)
//
#include <hip/hip_runtime.h>
#include <hip/hip_bf16.h>

typedef __attribute__((ext_vector_type(8)))  short          bf16x8;
typedef __attribute__((ext_vector_type(4)))  float          f32x4;
typedef __attribute__((ext_vector_type(16))) float          f32x16;
typedef __attribute__((ext_vector_type(8)))  unsigned short us8;

__device__ __forceinline__ unsigned short f2b(float f) {
  union { __hip_bfloat16 h; unsigned short u; } v;
  v.h = __float2bfloat16(f);
  return v.u;
}
__device__ __forceinline__ float b2f(unsigned short u) {
  union { unsigned u; float f; } v; v.u = ((unsigned)u) << 16; return v.f;
}
__device__ __forceinline__ float sigf(float x) {
  return __builtin_amdgcn_rcpf(1.f + __expf(-x));
}
__device__ __forceinline__ float tanhf_(float x) {
  return 2.f * __builtin_amdgcn_rcpf(1.f + __expf(-2.f * x)) - 1.f;
}

// ---------- conversion kernels ----------

__global__ __launch_bounds__(256) void conv_e(const float* __restrict__ in,
                                              unsigned short* __restrict__ out) {
  const size_t i = ((size_t)blockIdx.x * 256 + threadIdx.x) * 8;
  const float4 v0 = *(const float4*)(in + i);
  const float4 v1 = *(const float4*)(in + i + 4);
  us8 o;
  o[0]=f2b(v0.x); o[1]=f2b(v0.y); o[2]=f2b(v0.z); o[3]=f2b(v0.w);
  o[4]=f2b(v1.x); o[5]=f2b(v1.y); o[6]=f2b(v1.z); o[7]=f2b(v1.w);
  *(us8*)(out + i) = o;
}

__global__ __launch_bounds__(256) void conv_wT(const float* __restrict__ W,
                                               unsigned short* __restrict__ WT) {
  __shared__ float tile[64][65];
  const int bx = blockIdx.x & 63;
  const int by = blockIdx.x >> 6;
  const int tc = threadIdx.x & 63, tr = threadIdx.x >> 6;
  #pragma unroll
  for (int i = 0; i < 16; ++i) {
    const int r = i * 4 + tr;
    tile[r][tc] = W[(size_t)(by * 64 + r) * 4096 + bx * 64 + tc];
  }
  __syncthreads();
  #pragma unroll
  for (int i = 0; i < 16; ++i) {
    const int c = i * 4 + tr;
    WT[(size_t)(bx * 64 + c) * 1024 + by * 64 + tc] = f2b(tile[tc][c]);
  }
}

// W_h [1024][4096] f32 -> packed bf16 MFMA-B fragments:
// frag id = np*128 + nt*64 + kg; lane l holds B[k=kg*16+(l>>5)*8+j][zl=nt*32+(l&31)]
// where zcol = (zl>>4)*1024 + np*16 + (zl&15)  (gate-major 4H layout).
__global__ __launch_bounds__(256) void conv_whp(const float* __restrict__ Wh,
                                                unsigned short* __restrict__ Wp) {
  const int id = blockIdx.x * 256 + threadIdx.x;   // 524288 total
  const int l  = id & 63;
  const int kg = (id >> 6) & 63;
  const int nt = (id >> 12) & 1;
  const int np = id >> 13;
  const int zl = nt * 32 + (l & 31);
  const int col = (zl >> 4) * 1024 + np * 16 + (zl & 15);
  const int k0 = kg * 16 + (l >> 5) * 8;
  us8 o;
  #pragma unroll
  for (int j = 0; j < 8; ++j) o[j] = f2b(Wh[(size_t)(k0 + j) * 4096 + col]);
  *(us8*)(Wp + (size_t)id * 8) = o;
}

// ---------- xproj GEMM (unchanged, verified) ----------
__global__ __launch_bounds__(256) void gemm_xproj(const unsigned short* __restrict__ A,
                                                  const unsigned short* __restrict__ B,
                                                  unsigned short* __restrict__ C) {
  __shared__ unsigned short Alds[128 * 64];
  __shared__ unsigned short Blds[128 * 64];
  const int tid = threadIdx.x, lane = tid & 63, wv = tid >> 6;
  const int wm = wv >> 1, wn = wv & 1;
  const int bn = blockIdx.x & 31, bm = blockIdx.x >> 5;
  f32x4 acc[4][4] = {};
  const int srow = wv * 8 + (lane >> 3);
  const int sinner = (lane & 7) * 8;
  for (int kt = 0; kt < 16; ++kt) {
    #pragma unroll
    for (int rd = 0; rd < 4; ++rd) {
      const int row = rd * 32 + srow;
      const unsigned short* ga = A + (size_t)(bm * 128 + row) * 1024 + kt * 64 + sinner;
      const unsigned short* gb = B + (size_t)(bn * 128 + row) * 1024 + kt * 64 + sinner;
      __builtin_amdgcn_global_load_lds(
          (const __attribute__((address_space(1))) unsigned short*)ga,
          (__attribute__((address_space(3))) unsigned short*)(Alds + rd * 2048 + wv * 512),
          16, 0, 0);
      __builtin_amdgcn_global_load_lds(
          (const __attribute__((address_space(1))) unsigned short*)gb,
          (__attribute__((address_space(3))) unsigned short*)(Blds + rd * 2048 + wv * 512),
          16, 0, 0);
    }
    __syncthreads();
    #pragma unroll
    for (int ks = 0; ks < 2; ++ks) {
      const int kk = ks * 32 + (lane >> 4) * 8;
      bf16x8 af[4], bfr[4];
      #pragma unroll
      for (int mt = 0; mt < 4; ++mt)
        af[mt] = *(const bf16x8*)(Alds + (wm * 64 + mt * 16 + (lane & 15)) * 64 + kk);
      #pragma unroll
      for (int nt = 0; nt < 4; ++nt)
        bfr[nt] = *(const bf16x8*)(Blds + (wn * 64 + nt * 16 + (lane & 15)) * 64 + kk);
      #pragma unroll
      for (int mt = 0; mt < 4; ++mt)
        #pragma unroll
        for (int nt = 0; nt < 4; ++nt)
          acc[mt][nt] = __builtin_amdgcn_mfma_f32_16x16x32_bf16(af[mt], bfr[nt], acc[mt][nt], 0, 0, 0);
    }
    __syncthreads();
  }
  #pragma unroll
  for (int mt = 0; mt < 4; ++mt) {
    const int row0 = bm * 128 + wm * 64 + mt * 16 + (lane >> 4) * 4;
    #pragma unroll
    for (int nt = 0; nt < 4; ++nt) {
      const int col = bn * 128 + wn * 64 + nt * 16 + (lane & 15);
      #pragma unroll
      for (int r = 0; r < 4; ++r)
        C[(size_t)(row0 + r) * 4096 + col] = f2b(acc[mt][nt][r]);
    }
  }
}

// ---------- persistent recurrence kernel ----------
// grid 256, 1 block/CU. Block (m = batch slice of 32, n = h-col slice of 16).
// Waves (kh = wv&1 K-half, nh = wv>>1 zcol-half). W_h frags live in VGPRs (32/wave).
// A (h frags): each wave coherently loads its own 16 frags, shares via LDS (64KB).
// xproj prefetched across the barrier (latency hidden under poll).
// Barrier: distributed flags, tight spin, all waves poll, no post-poll syncthreads
// (double-buffer + flag-before-poll tolerates 1-step skew; LDS hazards covered by
// the pre-flag __syncthreads).
__global__ __launch_bounds__(256, 1) void lstm_recur(
    const unsigned short* __restrict__ xproj,  // [65536][4096] bf16
    const unsigned short* __restrict__ Wp,     // packed fragments
    const float* __restrict__ bias,            // [4096]
    unsigned short* __restrict__ hbuf,         // [2][131072] packed h fragments
    float* __restrict__ out,                   // [512][128][1024]
    unsigned* __restrict__ sync) {
  __shared__ unsigned short Alds[64 * 512];    // 64 frags x 1KB = 64KB
  __shared__ float zpart[2][32][67];           // K-half partials, padded
  const int tid = threadIdx.x;
  const int lane = tid & 63;
  const int wv = tid >> 6;
  const int kh = wv & 1;
  const int nh = wv >> 1;
  const int bid = blockIdx.x;
  const int m = (bid & 7) >> 1;
  const int n = ((bid & 1) << 5) | (bid >> 3);
  const int urow = tid >> 3;
  const int uhc = (tid & 7) * 2;
  const int hcol0 = n * 16 + uhc;
  const int ownk0 = kh * 32 + nh * 16;
  const int sibk0 = kh * 32 + (1 - nh) * 16;

  // preload this wave's 32 W_h fragments into VGPRs (held for the whole kernel)
  bf16x8 wO[16], wS[16];
  {
    const unsigned short* wb = Wp + (size_t)(n * 2 + nh) * 64 * 512 + lane * 8;
    #pragma unroll
    for (int i = 0; i < 16; ++i) wO[i] = *(const bf16x8*)(wb + (ownk0 + i) * 512);
    #pragma unroll
    for (int i = 0; i < 16; ++i) wS[i] = *(const bf16x8*)(wb + (sibk0 + i) * 512);
  }

  // hoisted bias
  const float2 bb0 = *(const float2*)(bias +        hcol0);
  const float2 bb1 = *(const float2*)(bias + 1024 + hcol0);
  const float2 bb2 = *(const float2*)(bias + 2048 + hcol0);
  const float2 bb3 = *(const float2*)(bias + 3072 + hcol0);

  float creg0 = 0.f, creg1 = 0.f;
  unsigned* flg = sync + m * 64;
  const size_t xoff = ((size_t)(m * 32) + urow) * 4096 + hcol0;

  // prologue: issue xproj loads for step 0
  unsigned xu0, xu1, xu2, xu3;
  {
    const unsigned short* xpp = xproj + xoff;
    asm volatile("global_load_dword %0, %1, off" : "=v"(xu0) : "v"(xpp));
    asm volatile("global_load_dword %0, %1, off" : "=v"(xu1) : "v"(xpp + 1024));
    asm volatile("global_load_dword %0, %1, off" : "=v"(xu2) : "v"(xpp + 2048));
    asm volatile("global_load_dword %0, %1, off" : "=v"(xu3) : "v"(xpp + 3072));
  }

  for (int t = 0; t < 511; ++t) {
    const unsigned short* hsrc = hbuf + (t & 1) * 131072;
    unsigned short* hdst = hbuf + ((t & 1) ^ 1) * 131072;

    // ---- 1. issue own A-loads (coherent), full drain (also retires xp/out) ----
    bf16x8 av[16];
    const unsigned short* ab = hsrc + (m * 64 + ownk0) * 512 + lane * 8;
    __builtin_amdgcn_sched_barrier(0);
    #pragma unroll
    for (int i = 0; i < 16; ++i)
      asm volatile("global_load_dwordx4 %0, %1, off sc0 sc1"
                   : "=v"(av[i]) : "v"(ab + i * 512));
    asm volatile("s_waitcnt vmcnt(0)" ::: "memory");
    __builtin_amdgcn_sched_barrier(0);

    // ---- 2. stage own frags to LDS for the sibling wave ----
    #pragma unroll
    for (int i = 0; i < 16; ++i)
      *(bf16x8*)(Alds + (ownk0 + i) * 512 + lane * 8) = av[i];
    __syncthreads();

    // ---- 3. MFMA: own frags from regs, sibling frags from LDS; W from VGPRs ----
    f32x16 a0, a1, a2, a3;
    #pragma unroll
    for (int r = 0; r < 16; ++r) { a0[r] = 0.f; a1[r] = 0.f; a2[r] = 0.f; a3[r] = 0.f; }
    #pragma unroll
    for (int i = 0; i < 16; i += 2) {
      a0 = __builtin_amdgcn_mfma_f32_32x32x16_bf16(av[i],     wO[i],     a0, 0, 0, 0);
      a1 = __builtin_amdgcn_mfma_f32_32x32x16_bf16(av[i + 1], wO[i + 1], a1, 0, 0, 0);
    }
    #pragma unroll
    for (int i = 0; i < 16; i += 2) {
      const bf16x8 s0 = *(const bf16x8*)(Alds + (sibk0 + i) * 512 + lane * 8);
      const bf16x8 s1 = *(const bf16x8*)(Alds + (sibk0 + i + 1) * 512 + lane * 8);
      a2 = __builtin_amdgcn_mfma_f32_32x32x16_bf16(s0, wS[i],     a2, 0, 0, 0);
      a3 = __builtin_amdgcn_mfma_f32_32x32x16_bf16(s1, wS[i + 1], a3, 0, 0, 0);
    }

    // ---- 4. dump partials (C/D: col=lane&31, row=(r&3)+8*(r>>2)+4*(lane>>5)) ----
    #pragma unroll
    for (int r = 0; r < 16; ++r) {
      const int zr = (r & 3) + 8 * (r >> 2) + 4 * (lane >> 5);
      zpart[kh][zr][nh * 32 + (lane & 31)] = (a0[r] + a1[r]) + (a2[r] + a3[r]);
    }
    __syncthreads();

    // ---- 5. reduce + activations ----
    float zc[4][2];
    #pragma unroll
    for (int g = 0; g < 4; ++g)
      #pragma unroll
      for (int j = 0; j < 2; ++j) {
        const int col = g * 16 + uhc + j;
        zc[g][j] = zpart[0][urow][col] + zpart[1][urow][col];
      }

    float hv0, hv1;
    {
      const float zg = zc[0][0] + b2f((unsigned short)(xu0 & 0xffffu)) + bb0.x;
      const float zi = zc[1][0] + b2f((unsigned short)(xu1 & 0xffffu)) + bb1.x;
      const float zf = zc[2][0] + b2f((unsigned short)(xu2 & 0xffffu)) + bb2.x;
      const float zo = zc[3][0] + b2f((unsigned short)(xu3 & 0xffffu)) + bb3.x;
      creg0 = tanhf_(zg) * sigf(zi) + creg0 * sigf(zf);
      hv0 = tanhf_(creg0) * sigf(zo);
    }
    {
      const float zg = zc[0][1] + b2f((unsigned short)(xu0 >> 16)) + bb0.y;
      const float zi = zc[1][1] + b2f((unsigned short)(xu1 >> 16)) + bb1.y;
      const float zf = zc[2][1] + b2f((unsigned short)(xu2 >> 16)) + bb2.y;
      const float zo = zc[3][1] + b2f((unsigned short)(xu3 >> 16)) + bb3.y;
      creg1 = tanhf_(zg) * sigf(zi) + creg1 * sigf(zf);
      hv1 = tanhf_(creg1) * sigf(zo);
    }

    if (t < 510) {
      // h frag store (consumer layout) -> drain -> block sync -> flag
      const unsigned hp = (unsigned)f2b(hv0) | ((unsigned)f2b(hv1) << 16);
      unsigned* hd = (unsigned*)(hdst + (m * 64 + n) * 512)
                   + (urow + 32 * (uhc >> 3)) * 4 + ((uhc & 7) >> 1);
      __hip_atomic_store(hd, hp, __ATOMIC_RELAXED, __HIP_MEMORY_SCOPE_AGENT);
      asm volatile("s_waitcnt vmcnt(0)" ::: "memory");
      __syncthreads();
      if (tid == 0)
        __hip_atomic_store(flg + n, (unsigned)(t + 1), __ATOMIC_RELAXED, __HIP_MEMORY_SCOPE_AGENT);
    }

    // out[t+1] = h after step t (out[0]=0 via memset); rides through poll phase
    float2 ho; ho.x = hv0; ho.y = hv1;
    *(float2*)(out + ((size_t)(t + 1) * 128 + m * 32 + urow) * 1024 + hcol0) = ho;

    if (t < 510) {
      // prefetch next step's xproj (latency hides under the poll)
      const unsigned short* xpp = xproj + (size_t)(t + 1) * 524288 + xoff;
      asm volatile("global_load_dword %0, %1, off" : "=v"(xu0) : "v"(xpp));
      asm volatile("global_load_dword %0, %1, off" : "=v"(xu1) : "v"(xpp + 1024));
      asm volatile("global_load_dword %0, %1, off" : "=v"(xu2) : "v"(xpp + 2048));
      asm volatile("global_load_dword %0, %1, off" : "=v"(xu3) : "v"(xpp + 3072));
      // tight poll, all waves independently; lane i watches flag i
      unsigned v;
      do {
        v = __hip_atomic_load(flg + lane, __ATOMIC_RELAXED, __HIP_MEMORY_SCOPE_AGENT);
      } while (!__all((int)(v > (unsigned)t)));
    }
  }
}

extern "C" void kernel_launch(void* const* d_in, const int* in_sizes, int n_in,
                              void* d_out, int out_size, void* d_ws, size_t ws_size,
                              hipStream_t stream) {
  (void)in_sizes; (void)n_in; (void)out_size; (void)ws_size;
  const float* embeds = (const float*)d_in[0];
  const float* Wx     = (const float*)d_in[1];
  const float* Wh     = (const float*)d_in[2];
  const float* bias   = (const float*)d_in[3];
  float* out = (float*)d_out;

  char* w = (char*)d_ws;
  unsigned short* eb  = (unsigned short*)(w);                 // 134,217,728 B
  unsigned short* WxT = (unsigned short*)(w + 134217728);     //   8,388,608 B
  unsigned short* Whp = (unsigned short*)(w + 142606336);     //   8,388,608 B
  unsigned short* xp  = (unsigned short*)(w + 150994944);     // 536,870,912 B
  unsigned short* hb  = (unsigned short*)(w + 687865856);     //     524,288 B
  unsigned*       sy  = (unsigned*)(w + 688390144);           //       1,024 B

  hipMemsetAsync(d_out, 0, (size_t)128 * 1024 * sizeof(float), stream);
  hipMemsetAsync(hb, 0, 262144, stream);
  hipMemsetAsync(sy, 0, 1024, stream);

  conv_e   <<<32768, 256, 0, stream>>>(embeds, eb);
  conv_wT  <<<1024,  256, 0, stream>>>(Wx, WxT);
  conv_whp <<<2048,  256, 0, stream>>>(Wh, Whp);
  gemm_xproj<<<16384, 256, 0, stream>>>(eb, WxT, xp);
  lstm_recur<<<256,   256, 0, stream>>>(xp, Whp, bias, hb, out, sy);
}

// Round 6
// 2925.694 us; speedup vs baseline: 1.2518x; 1.2518x over previous
//
#include <hip/hip_runtime.h>
#include <hip/hip_bf16.h>

typedef __attribute__((ext_vector_type(8)))  short          bf16x8;
typedef __attribute__((ext_vector_type(4)))  float          f32x4;
typedef __attribute__((ext_vector_type(8)))  unsigned short us8;

__device__ __forceinline__ unsigned short f2b(float f) {
  union { __hip_bfloat16 h; unsigned short u; } v;
  v.h = __float2bfloat16(f);
  return v.u;
}
__device__ __forceinline__ float b2f(unsigned short u) {
  union { unsigned u; float f; } v; v.u = ((unsigned)u) << 16; return v.f;
}
__device__ __forceinline__ float sigf(float x) {
  return __builtin_amdgcn_rcpf(1.f + __expf(-x));
}
__device__ __forceinline__ float tanhf_(float x) {
  return 2.f * __builtin_amdgcn_rcpf(1.f + __expf(-2.f * x)) - 1.f;
}

// ---------- conversion kernels ----------

__global__ __launch_bounds__(256) void conv_e(const float* __restrict__ in,
                                              unsigned short* __restrict__ out) {
  const size_t i = ((size_t)blockIdx.x * 256 + threadIdx.x) * 8;
  const float4 v0 = *(const float4*)(in + i);
  const float4 v1 = *(const float4*)(in + i + 4);
  us8 o;
  o[0]=f2b(v0.x); o[1]=f2b(v0.y); o[2]=f2b(v0.z); o[3]=f2b(v0.w);
  o[4]=f2b(v1.x); o[5]=f2b(v1.y); o[6]=f2b(v1.z); o[7]=f2b(v1.w);
  *(us8*)(out + i) = o;
}

__global__ __launch_bounds__(256) void conv_wT(const float* __restrict__ W,
                                               unsigned short* __restrict__ WT) {
  __shared__ float tile[64][65];
  const int bx = blockIdx.x & 63;
  const int by = blockIdx.x >> 6;
  const int tc = threadIdx.x & 63, tr = threadIdx.x >> 6;
  #pragma unroll
  for (int i = 0; i < 16; ++i) {
    const int r = i * 4 + tr;
    tile[r][tc] = W[(size_t)(by * 64 + r) * 4096 + bx * 64 + tc];
  }
  __syncthreads();
  #pragma unroll
  for (int i = 0; i < 16; ++i) {
    const int c = i * 4 + tr;
    WT[(size_t)(bx * 64 + c) * 1024 + by * 64 + tc] = f2b(tile[tc][c]);
  }
}

// W_h [1024][4096] f32 -> packed bf16 MFMA-B fragments.
// id = n*16384 + kq*4096 + nt*512 + kt*64 + lane. lane l holds B[k][zcol]:
// k = kq*256 + kt*32 + (l>>4)*8 + j; zi = nt*16 + (l&15);
// zcol = (zi>>5)*1024 + n*32 + (zi&31)  (gate-major 4H).
__global__ __launch_bounds__(256) void conv_whp(const float* __restrict__ Wh,
                                                unsigned short* __restrict__ Wp) {
  const int id = blockIdx.x * 256 + threadIdx.x;   // 524288 total
  const int l  = id & 63;
  const int kt = (id >> 6) & 7;
  const int nt = (id >> 9) & 7;
  const int kq = (id >> 12) & 3;
  const int n  = id >> 14;
  const int zi = nt * 16 + (l & 15);
  const int col = (zi >> 5) * 1024 + n * 32 + (zi & 31);
  const int k0 = kq * 256 + kt * 32 + (l >> 4) * 8;
  us8 o;
  #pragma unroll
  for (int j = 0; j < 8; ++j) o[j] = f2b(Wh[(size_t)(k0 + j) * 4096 + col]);
  *(us8*)(Wp + (size_t)id * 8) = o;
}

// ---------- xproj GEMM (unchanged, verified) ----------
__global__ __launch_bounds__(256) void gemm_xproj(const unsigned short* __restrict__ A,
                                                  const unsigned short* __restrict__ B,
                                                  unsigned short* __restrict__ C) {
  __shared__ unsigned short Alds[128 * 64];
  __shared__ unsigned short Blds[128 * 64];
  const int tid = threadIdx.x, lane = tid & 63, wv = tid >> 6;
  const int wm = wv >> 1, wn = wv & 1;
  const int bn = blockIdx.x & 31, bm = blockIdx.x >> 5;
  f32x4 acc[4][4] = {};
  const int srow = wv * 8 + (lane >> 3);
  const int sinner = (lane & 7) * 8;
  for (int kt = 0; kt < 16; ++kt) {
    #pragma unroll
    for (int rd = 0; rd < 4; ++rd) {
      const int row = rd * 32 + srow;
      const unsigned short* ga = A + (size_t)(bm * 128 + row) * 1024 + kt * 64 + sinner;
      const unsigned short* gb = B + (size_t)(bn * 128 + row) * 1024 + kt * 64 + sinner;
      __builtin_amdgcn_global_load_lds(
          (const __attribute__((address_space(1))) unsigned short*)ga,
          (__attribute__((address_space(3))) unsigned short*)(Alds + rd * 2048 + wv * 512),
          16, 0, 0);
      __builtin_amdgcn_global_load_lds(
          (const __attribute__((address_space(1))) unsigned short*)gb,
          (__attribute__((address_space(3))) unsigned short*)(Blds + rd * 2048 + wv * 512),
          16, 0, 0);
    }
    __syncthreads();
    #pragma unroll
    for (int ks = 0; ks < 2; ++ks) {
      const int kk = ks * 32 + (lane >> 4) * 8;
      bf16x8 af[4], bfr[4];
      #pragma unroll
      for (int mt = 0; mt < 4; ++mt)
        af[mt] = *(const bf16x8*)(Alds + (wm * 64 + mt * 16 + (lane & 15)) * 64 + kk);
      #pragma unroll
      for (int nt = 0; nt < 4; ++nt)
        bfr[nt] = *(const bf16x8*)(Blds + (wn * 64 + nt * 16 + (lane & 15)) * 64 + kk);
      #pragma unroll
      for (int mt = 0; mt < 4; ++mt)
        #pragma unroll
        for (int nt = 0; nt < 4; ++nt)
          acc[mt][nt] = __builtin_amdgcn_mfma_f32_16x16x32_bf16(af[mt], bfr[nt], acc[mt][nt], 0, 0, 0);
    }
    __syncthreads();
  }
  #pragma unroll
  for (int mt = 0; mt < 4; ++mt) {
    const int row0 = bm * 128 + wm * 64 + mt * 16 + (lane >> 4) * 4;
    #pragma unroll
    for (int nt = 0; nt < 4; ++nt) {
      const int col = bn * 128 + wn * 64 + nt * 16 + (lane & 15);
      #pragma unroll
      for (int r = 0; r < 4; ++r)
        C[(size_t)(row0 + r) * 4096 + col] = f2b(acc[mt][nt][r]);
    }
  }
}

// ---------- persistent recurrence kernel ----------
// 8 groups x 32 blocks (roles from blockIdx: m=bid>>5, n=bid&31).
// Block = 16 batch rows x 128 z-cols; W_h slice in 256 VGPRs; A-frags straight
// from row-major h (device-scope sc0 sc1 loads, R3-proven). Sync: private flag
// mailboxes — flags[consumer 256][producer 32]; producer broadcasts its tag to
// its group's 32 consumer slots (one 32-lane store, issue-only); each consumer
// tight-polls ONE private 128B line. No shared hot lines, no XCD assumptions,
// no startup negotiation. Protocol order identical to R3 (store->drain->sync->
// flag->poll), so no deadlock.
__global__ __launch_bounds__(256, 1) void lstm_recur(
    const unsigned short* __restrict__ xproj,  // [512*128][4096] bf16
    const unsigned short* __restrict__ Wp,     // packed fragments
    const float* __restrict__ bias,            // [4096]
    unsigned short* __restrict__ hbuf,         // [2][128][1024] bf16 row-major
    float* __restrict__ out,                   // [512][128][1024]
    unsigned* __restrict__ flags) {            // [256][32] private mailboxes
  __shared__ float zpart[10][16][132];         // [0..3] used; oversized -> 1 block/CU
  const int tid = threadIdx.x;
  const int lane = tid & 63;
  const int kq = tid >> 6;                     // wave = K-quarter
  const int m = blockIdx.x >> 5;               // group / 16-row batch stripe
  const int n = blockIdx.x & 31;               // 128-z-col slot

  // W_h fragments -> VGPRs (64 x bf16x8 = 256 VGPR/lane, held whole kernel)
  bf16x8 wf[64];
  {
    const unsigned short* wb = Wp + ((size_t)(n * 4 + kq) * 64) * 512 + lane * 8;
    #pragma unroll
    for (int f = 0; f < 64; ++f) wf[f] = *(const bf16x8*)(wb + f * 512);
  }

  const int r    = tid >> 4;                   // row within stripe (0..15)
  const int hg   = tid & 15;                   // h-col pair group
  const int hc0  = n * 32 + hg * 2;            // h col (0..1023)
  const int grow = m * 16 + r;                 // global batch row

  const float2 bb0 = *(const float2*)(bias +        hc0);
  const float2 bb1 = *(const float2*)(bias + 1024 + hc0);
  const float2 bb2 = *(const float2*)(bias + 2048 + hc0);
  const float2 bb3 = *(const float2*)(bias + 3072 + hc0);

  float cr0 = 0.f, cr1 = 0.f;
  const size_t xbase = (size_t)grow * 4096 + hc0;
  unsigned* bcast = flags + (m * 32 + (lane & 31)) * 32 + n;  // producer->consumer slots
  const unsigned* myf = flags + (size_t)(m * 32 + n) * 32 + (lane & 31);  // my private line

  // prologue: xproj loads for step 0
  unsigned xu0, xu1, xu2, xu3;
  {
    const unsigned short* xpp = xproj + xbase;
    asm volatile("global_load_dword %0, %1, off" : "=v"(xu0) : "v"(xpp));
    asm volatile("global_load_dword %0, %1, off" : "=v"(xu1) : "v"(xpp + 1024));
    asm volatile("global_load_dword %0, %1, off" : "=v"(xu2) : "v"(xpp + 2048));
    asm volatile("global_load_dword %0, %1, off" : "=v"(xu3) : "v"(xpp + 3072));
  }

  // A-frag addr: row (lane&15) of stripe, k = kq*256 + (lane>>4)*8 (+kt*32 imm)
  const size_t aoff = ((size_t)(m * 16 + (lane & 15))) * 1024 + kq * 256 + (lane >> 4) * 8;

  for (int t = 0; t < 511; ++t) {
    const unsigned short* ab = hbuf + (t & 1) * 131072 + aoff;

    bf16x8 av0, av1, av2, av3, av4, av5, av6, av7;
    __builtin_amdgcn_sched_barrier(0);
    asm volatile("global_load_dwordx4 %0, %1, off sc0 sc1"            : "=v"(av0) : "v"(ab));
    asm volatile("global_load_dwordx4 %0, %1, off offset:64 sc0 sc1"  : "=v"(av1) : "v"(ab));
    asm volatile("global_load_dwordx4 %0, %1, off offset:128 sc0 sc1" : "=v"(av2) : "v"(ab));
    asm volatile("global_load_dwordx4 %0, %1, off offset:192 sc0 sc1" : "=v"(av3) : "v"(ab));
    asm volatile("global_load_dwordx4 %0, %1, off offset:256 sc0 sc1" : "=v"(av4) : "v"(ab));
    asm volatile("global_load_dwordx4 %0, %1, off offset:320 sc0 sc1" : "=v"(av5) : "v"(ab));
    asm volatile("global_load_dwordx4 %0, %1, off offset:384 sc0 sc1" : "=v"(av6) : "v"(ab));
    asm volatile("global_load_dwordx4 %0, %1, off offset:448 sc0 sc1" : "=v"(av7) : "v"(ab));
    asm volatile("s_waitcnt vmcnt(0)" ::: "memory");
    __builtin_amdgcn_sched_barrier(0);

    // MFMA: 8 n-tiles x 8 k-tiles of 16x16x32; acc reuse distance 8
    f32x4 ac0 = {0.f,0.f,0.f,0.f}, ac1 = {0.f,0.f,0.f,0.f};
    f32x4 ac2 = {0.f,0.f,0.f,0.f}, ac3 = {0.f,0.f,0.f,0.f};
    f32x4 ac4 = {0.f,0.f,0.f,0.f}, ac5 = {0.f,0.f,0.f,0.f};
    f32x4 ac6 = {0.f,0.f,0.f,0.f}, ac7 = {0.f,0.f,0.f,0.f};
#define MF_STEP(AV, KT) \
    ac0 = __builtin_amdgcn_mfma_f32_16x16x32_bf16(AV, wf[ 0 + KT], ac0, 0, 0, 0); \
    ac1 = __builtin_amdgcn_mfma_f32_16x16x32_bf16(AV, wf[ 8 + KT], ac1, 0, 0, 0); \
    ac2 = __builtin_amdgcn_mfma_f32_16x16x32_bf16(AV, wf[16 + KT], ac2, 0, 0, 0); \
    ac3 = __builtin_amdgcn_mfma_f32_16x16x32_bf16(AV, wf[24 + KT], ac3, 0, 0, 0); \
    ac4 = __builtin_amdgcn_mfma_f32_16x16x32_bf16(AV, wf[32 + KT], ac4, 0, 0, 0); \
    ac5 = __builtin_amdgcn_mfma_f32_16x16x32_bf16(AV, wf[40 + KT], ac5, 0, 0, 0); \
    ac6 = __builtin_amdgcn_mfma_f32_16x16x32_bf16(AV, wf[48 + KT], ac6, 0, 0, 0); \
    ac7 = __builtin_amdgcn_mfma_f32_16x16x32_bf16(AV, wf[56 + KT], ac7, 0, 0, 0);
    MF_STEP(av0, 0) MF_STEP(av1, 1) MF_STEP(av2, 2) MF_STEP(av3, 3)
    MF_STEP(av4, 4) MF_STEP(av5, 5) MF_STEP(av6, 6) MF_STEP(av7, 7)
#undef MF_STEP

    // dump partials: 16x16 C/D: col=lane&15, row=(lane>>4)*4+reg
    {
      const int crow = (lane >> 4) * 4, ccol = lane & 15;
#define DUMP(NT, AC) \
      zpart[kq][crow + 0][NT * 16 + ccol] = AC[0]; \
      zpart[kq][crow + 1][NT * 16 + ccol] = AC[1]; \
      zpart[kq][crow + 2][NT * 16 + ccol] = AC[2]; \
      zpart[kq][crow + 3][NT * 16 + ccol] = AC[3];
      DUMP(0, ac0) DUMP(1, ac1) DUMP(2, ac2) DUMP(3, ac3)
      DUMP(4, ac4) DUMP(5, ac5) DUMP(6, ac6) DUMP(7, ac7)
#undef DUMP
    }
    __syncthreads();

    // cross-wave K reduction: local z-col = g*32 + (hg*2+j)
    float zc[4][2];
    #pragma unroll
    for (int g = 0; g < 4; ++g)
      #pragma unroll
      for (int j = 0; j < 2; ++j) {
        const int col = g * 32 + hg * 2 + j;
        zc[g][j] = (zpart[0][r][col] + zpart[1][r][col])
                 + (zpart[2][r][col] + zpart[3][r][col]);
      }

    float hv0, hv1;
    {
      const float zg = zc[0][0] + b2f((unsigned short)(xu0 & 0xffffu)) + bb0.x;
      const float zi = zc[1][0] + b2f((unsigned short)(xu1 & 0xffffu)) + bb1.x;
      const float zf = zc[2][0] + b2f((unsigned short)(xu2 & 0xffffu)) + bb2.x;
      const float zo = zc[3][0] + b2f((unsigned short)(xu3 & 0xffffu)) + bb3.x;
      cr0 = tanhf_(zg) * sigf(zi) + cr0 * sigf(zf);
      hv0 = tanhf_(cr0) * sigf(zo);
    }
    {
      const float zg = zc[0][1] + b2f((unsigned short)(xu0 >> 16)) + bb0.y;
      const float zi = zc[1][1] + b2f((unsigned short)(xu1 >> 16)) + bb1.y;
      const float zf = zc[2][1] + b2f((unsigned short)(xu2 >> 16)) + bb2.y;
      const float zo = zc[3][1] + b2f((unsigned short)(xu3 >> 16)) + bb3.y;
      cr1 = tanhf_(zg) * sigf(zi) + cr1 * sigf(zf);
      hv1 = tanhf_(cr1) * sigf(zo);
    }

    if (t < 510) {
      // h store (device scope) -> per-wave drain -> block sync -> flag broadcast
      const unsigned hp = (unsigned)f2b(hv0) | ((unsigned)f2b(hv1) << 16);
      unsigned short* hd = hbuf + ((t & 1) ^ 1) * 131072 + (size_t)grow * 1024 + hc0;
      asm volatile("global_store_dword %0, %1, off sc0 sc1" :: "v"(hd), "v"(hp) : "memory");
      asm volatile("s_waitcnt vmcnt(0)" ::: "memory");
      __syncthreads();
      if (kq == 0 && lane < 32) {
        const unsigned g1 = (unsigned)(t + 1);
        asm volatile("global_store_dword %0, %1, off sc0 sc1" :: "v"(bcast), "v"(g1) : "memory");
      }
    }

    // out[t+1] = h after step t (out[0]=0 via memset); rides through poll phase
    float2 ho; ho.x = hv0; ho.y = hv1;
    *(float2*)(out + ((size_t)(t + 1) * 128 + grow) * 1024 + hc0) = ho;

    if (t < 510) {
      // prefetch next xproj (latency hides under the poll)
      const unsigned short* xpp = xproj + (size_t)(t + 1) * 524288 + xbase;
      asm volatile("global_load_dword %0, %1, off" : "=v"(xu0) : "v"(xpp));
      asm volatile("global_load_dword %0, %1, off" : "=v"(xu1) : "v"(xpp + 1024));
      asm volatile("global_load_dword %0, %1, off" : "=v"(xu2) : "v"(xpp + 2048));
      asm volatile("global_load_dword %0, %1, off" : "=v"(xu3) : "v"(xpp + 3072));
      // poll MY private mailbox line: lane i watches producer (i&31)
      unsigned v;
      do {
        asm volatile("global_load_dword %0, %1, off sc0 sc1" : "=v"(v) : "v"(myf));
        asm volatile("s_waitcnt vmcnt(0)" ::: "memory");
      } while (__any((int)v <= t));
    }
  }
}

extern "C" void kernel_launch(void* const* d_in, const int* in_sizes, int n_in,
                              void* d_out, int out_size, void* d_ws, size_t ws_size,
                              hipStream_t stream) {
  (void)in_sizes; (void)n_in; (void)out_size; (void)ws_size;
  const float* embeds = (const float*)d_in[0];
  const float* Wx     = (const float*)d_in[1];
  const float* Wh     = (const float*)d_in[2];
  const float* bias   = (const float*)d_in[3];
  float* out = (float*)d_out;

  char* w = (char*)d_ws;
  unsigned short* eb  = (unsigned short*)(w);                 // 134,217,728 B
  unsigned short* WxT = (unsigned short*)(w + 134217728);     //   8,388,608 B
  unsigned short* Whp = (unsigned short*)(w + 142606336);     //   8,388,608 B
  unsigned short* xp  = (unsigned short*)(w + 150994944);     // 536,870,912 B
  unsigned short* hb  = (unsigned short*)(w + 687865856);     //     524,288 B
  unsigned*       fl  = (unsigned*)(w + 688390144);           //      32,768 B

  hipMemsetAsync(d_out, 0, (size_t)128 * 1024 * sizeof(float), stream);
  hipMemsetAsync(hb, 0, 524288, stream);
  hipMemsetAsync(fl, 0, 32768, stream);

  conv_e   <<<32768, 256, 0, stream>>>(embeds, eb);
  conv_wT  <<<1024,  256, 0, stream>>>(Wx, WxT);
  conv_whp <<<2048,  256, 0, stream>>>(Wh, Whp);
  gemm_xproj<<<16384, 256, 0, stream>>>(eb, WxT, xp);
  lstm_recur<<<256,   256, 0, stream>>>(xp, Whp, bias, hb, out, fl);
}